// Round 1
// baseline (2818.776 us; speedup 1.0000x reference)
//
#include <hip/hip_runtime.h>
#include <hip/hip_bf16.h>

#define BB 8
#define NN 2048
#define MM 2048
#define FF 64
#define ND (NN + MM - 1)
#define INF __builtin_inff()

static_assert(NN == MM, "diag-offset closed form assumes N==M");

// ---- packed anti-diagonal layout helpers (N==M) ----
// diagonal d holds i in [imin(d), imax(d)], stored at off(d) + (i - imin(d))
__device__ __forceinline__ int diag_imin(int d) { return d > (MM - 1) ? d - (MM - 1) : 0; }
__device__ __forceinline__ int diag_off(int d) {
  if (d < NN) return d * (d + 1) / 2;
  int e = d - NN;
  return NN * (NN + 1) / 2 + e * (NN - 1) - e * (e - 1) / 2;
}

__device__ __forceinline__ void store_elem(float* p, float v) { *p = v; }
__device__ __forceinline__ void store_elem(__hip_bfloat16* p, float v) { *p = __float2bfloat16(v); }
__device__ __forceinline__ float load_elem(const float* p) { return *p; }
__device__ __forceinline__ float load_elem(const __hip_bfloat16* p) { return __bfloat162float(*p); }

// ---------------- row norms: x2[r] = sum_k x[r][k]^2 ----------------
__global__ void norms_k(const float* __restrict__ a, float* __restrict__ o, int rows) {
  int r = blockIdx.x * 256 + threadIdx.x;
  if (r >= rows) return;
  const float4* p = (const float4*)(a + (size_t)r * FF);
  float s = 0.f;
#pragma unroll
  for (int q = 0; q < FF / 4; ++q) {
    float4 v = p[q];
    s = fmaf(v.x, v.x, fmaf(v.y, v.y, fmaf(v.z, v.z, fmaf(v.w, v.w, s))));
  }
  o[r] = s;
}

// ---------------- dist tile kernel ----------------
// 64x64 (i,j) tile per WG; fp32 dot via LDS; writes dist in diag-packed order.
template <typename T>
__global__ __launch_bounds__(256) void dist_k(const float* __restrict__ X,
                                              const float* __restrict__ Y,
                                              const float* __restrict__ x2,
                                              const float* __restrict__ y2,
                                              T* __restrict__ dist) {
  __shared__ float xs[64][68];   // x tile row-major; reused as staged dist tile
  __shared__ float ysT[64][68];  // y tile transposed: ysT[k][j]
  const int b = blockIdx.z, i0 = blockIdx.y * 64, j0 = blockIdx.x * 64;
  const int tid = threadIdx.x, tx = tid & 15, ty = tid >> 4;
  const float* Xb = X + ((size_t)b * NN + i0) * FF;
  const float* Yb = Y + ((size_t)b * MM + j0) * FF;
#pragma unroll
  for (int rep = 0; rep < 4; ++rep) {
    int row = rep * 16 + ty;
    float4 vx = *(const float4*)(Xb + row * FF + tx * 4);
    *(float4*)&xs[row][tx * 4] = vx;
    float4 vy = *(const float4*)(Yb + row * FF + tx * 4);
    ysT[tx * 4 + 0][row] = vy.x;
    ysT[tx * 4 + 1][row] = vy.y;
    ysT[tx * 4 + 2][row] = vy.z;
    ysT[tx * 4 + 3][row] = vy.w;
  }
  __syncthreads();

  const int il0 = ty * 4, jl0 = tx * 4;
  float c[4][4] = {};
#pragma unroll
  for (int k = 0; k < FF; ++k) {
    float a0 = xs[il0 + 0][k], a1 = xs[il0 + 1][k], a2 = xs[il0 + 2][k], a3 = xs[il0 + 3][k];
    float4 bv = *(const float4*)&ysT[k][jl0];
    c[0][0] = fmaf(a0, bv.x, c[0][0]); c[0][1] = fmaf(a0, bv.y, c[0][1]);
    c[0][2] = fmaf(a0, bv.z, c[0][2]); c[0][3] = fmaf(a0, bv.w, c[0][3]);
    c[1][0] = fmaf(a1, bv.x, c[1][0]); c[1][1] = fmaf(a1, bv.y, c[1][1]);
    c[1][2] = fmaf(a1, bv.z, c[1][2]); c[1][3] = fmaf(a1, bv.w, c[1][3]);
    c[2][0] = fmaf(a2, bv.x, c[2][0]); c[2][1] = fmaf(a2, bv.y, c[2][1]);
    c[2][2] = fmaf(a2, bv.z, c[2][2]); c[2][3] = fmaf(a2, bv.w, c[2][3]);
    c[3][0] = fmaf(a3, bv.x, c[3][0]); c[3][1] = fmaf(a3, bv.y, c[3][1]);
    c[3][2] = fmaf(a3, bv.z, c[3][2]); c[3][3] = fmaf(a3, bv.w, c[3][3]);
  }

  float x2v[4], y2v[4];
#pragma unroll
  for (int p = 0; p < 4; ++p) x2v[p] = x2[b * NN + i0 + il0 + p];
#pragma unroll
  for (int q = 0; q < 4; ++q) y2v[q] = y2[b * MM + j0 + jl0 + q];
  __syncthreads();  // all xs reads done; safe to overwrite with dist values
#pragma unroll
  for (int p = 0; p < 4; ++p) {
    float4 r;
    r.x = sqrtf(fmaxf(x2v[p] + y2v[0] - 2.f * c[p][0], 0.f));
    r.y = sqrtf(fmaxf(x2v[p] + y2v[1] - 2.f * c[p][1], 0.f));
    r.z = sqrtf(fmaxf(x2v[p] + y2v[2] - 2.f * c[p][2], 0.f));
    r.w = sqrtf(fmaxf(x2v[p] + y2v[3] - 2.f * c[p][3], 0.f));
    *(float4*)&xs[il0 + p][jl0] = r;
  }
  __syncthreads();

  // anti-diagonal write-out: lane l reads cs[l][(c-l)&63] -> contiguous global segments
  const int lane = tid & 63, w = tid >> 6;
  T* db = dist + (size_t)b * NN * MM;
#pragma unroll
  for (int s = 0; s < 16; ++s) {
    int cdi = w * 16 + s;
    int jl = (cdi - lane) & 63;
    int dl = lane + jl;  // == cdi or cdi + 64
    int d = i0 + j0 + dl;
    int idx = diag_off(d) + (i0 + lane - diag_imin(d));
    store_elem(&db[idx], xs[lane][jl]);
  }
}

// ---------------- DP wavefront ----------------
// one WG per batch; 256 threads x 8 cells; diagonals in registers,
// boundary cell via 3-slot rotating LDS; one barrier per diagonal;
// next-diagonal dist prefetched at step start.
template <typename T, bool FIRST>
__device__ __forceinline__ void dp_step(const T* __restrict__ db, int d, int& off,
                                        float (&p1)[8], float (&p2)[8],
                                        float (&dvC)[8], float (&dvN)[8],
                                        float (*bnd)[256], int t) {
  const int ibase = t * 8;
  const int imin = diag_imin(d);
  const int imax = (d < NN) ? d : NN - 1;

  // ---- prefetch dist for d+1 (issued before compute; waited next step) ----
  const int dn = d + 1;
  const int offn = off + (imax - imin + 1);
  if (dn < ND) {
    const int iminn = diag_imin(dn);
    const int imaxn = (dn < NN) ? dn : NN - 1;
    const T* src = db + (offn - iminn);
    bool fastn = (ibase >= iminn) && (ibase + 7 <= imaxn);
    if (fastn) {
#pragma unroll
      for (int q = 0; q < 8; ++q) dvN[q] = load_elem(&src[ibase + q]);
    } else {
#pragma unroll
      for (int q = 0; q < 8; ++q) {
        int i = ibase + q;
        bool v = (i >= iminn) && (i <= imaxn);
        dvN[q] = v ? load_elem(&src[i]) : INF;
      }
    }
  }
  off = offn;

  // ---- neighbor boundary (thread t-1's last cell, 1 and 2 diagonals ago) ----
  float p1n = t ? bnd[(d + 2) % 3][t - 1] : INF;
  float p2n = t ? bnd[(d + 1) % 3][t - 1] : INF;

  // ---- compute current diagonal in-place into p2 (descending q => no copies) ----
  bool fast = (ibase >= imin) && (ibase + 7 <= imax);
  {  // q = 7 first so the boundary LDS write issues early
    float cand = fminf(p1[7], fminf(p1[6], p2[6]));
    float cu;
    if (fast) cu = dvC[7] + cand;
    else {
      int i = ibase + 7;
      cu = ((i >= imin) && (i <= imax)) ? dvC[7] + cand : INF;
    }
    p2[7] = cu;
    bnd[d % 3][t] = cu;
  }
  if (fast) {
#pragma unroll
    for (int q = 6; q >= 1; --q) p2[q] = dvC[q] + fminf(p1[q], fminf(p1[q - 1], p2[q - 1]));
    float cand = fminf(p1[0], fminf(p1n, p2n));
    if (FIRST && t == 0) cand = 0.f;
    p2[0] = dvC[0] + cand;
  } else {
#pragma unroll
    for (int q = 6; q >= 1; --q) {
      float cand = fminf(p1[q], fminf(p1[q - 1], p2[q - 1]));
      int i = ibase + q;
      p2[q] = ((i >= imin) && (i <= imax)) ? dvC[q] + cand : INF;
    }
    float cand = fminf(p1[0], fminf(p1n, p2n));
    if (FIRST && t == 0) cand = 0.f;
    p2[0] = ((ibase >= imin) && (ibase <= imax)) ? dvC[0] + cand : INF;
  }
  __syncthreads();
}

template <typename T>
__global__ __launch_bounds__(256) void dp_k(const T* __restrict__ dist, float* __restrict__ out) {
  const int b = blockIdx.x, t = threadIdx.x;
  __shared__ float bnd[3][256];
  const T* db = dist + (size_t)b * NN * MM;
  float pa[8], pb[8], dvA[8], dvB[8];
#pragma unroll
  for (int q = 0; q < 8; ++q) { pa[q] = INF; pb[q] = INF; dvA[q] = INF; dvB[q] = INF; }
  bnd[0][t] = INF; bnd[1][t] = INF; bnd[2][t] = INF;
  if (t == 0) dvA[0] = load_elem(&db[0]);
  __syncthreads();

  int off = 0;
  dp_step<T, true>(db, 0, off, pa, pb, dvA, dvB, bnd, t);
  for (int d = 1; d < ND - 1; d += 2) {  // ND-1 = 4094 remaining steps, exactly 2047 pairs
    dp_step<T, false>(db, d, off, pb, pa, dvB, dvA, bnd, t);
    dp_step<T, false>(db, d + 1, off, pa, pb, dvA, dvB, bnd, t);
  }
  if (t == 255) out[b] = pb[7];  // D[N-1][M-1]
}

extern "C" void kernel_launch(void* const* d_in, const int* in_sizes, int n_in,
                              void* d_out, int out_size, void* d_ws, size_t ws_size,
                              hipStream_t stream) {
  const float* X = (const float*)d_in[0];
  const float* Y = (const float*)d_in[1];
  float* out = (float*)d_out;

  float* x2 = (float*)d_ws;      // BB*NN floats
  float* y2 = x2 + BB * NN;      // BB*MM floats
  const size_t normsBytes = (size_t)(BB * NN + BB * MM) * sizeof(float);
  char* distp = (char*)d_ws + normsBytes;
  const size_t needF32 = normsBytes + (size_t)BB * NN * MM * sizeof(float);

  norms_k<<<dim3((BB * NN + 255) / 256), dim3(256), 0, stream>>>(X, x2, BB * NN);
  norms_k<<<dim3((BB * MM + 255) / 256), dim3(256), 0, stream>>>(Y, y2, BB * MM);

  dim3 gd(MM / 64, NN / 64, BB);
  if (ws_size >= needF32) {
    dist_k<float><<<gd, dim3(256), 0, stream>>>(X, Y, x2, y2, (float*)distp);
    dp_k<float><<<dim3(BB), dim3(256), 0, stream>>>((const float*)distp, out);
  } else {  // bf16 dist storage (half the footprint/traffic; error << 2% threshold)
    dist_k<__hip_bfloat16><<<gd, dim3(256), 0, stream>>>(X, Y, x2, y2, (__hip_bfloat16*)distp);
    dp_k<__hip_bfloat16><<<dim3(BB), dim3(256), 0, stream>>>((const __hip_bfloat16*)distp, out);
  }
}

// Round 2
// 634.026 us; speedup vs baseline: 4.4458x; 4.4458x over previous
//
#include <hip/hip_runtime.h>
#include <hip/hip_bf16.h>

#define BB 8
#define NN 2048
#define MM 2048
#define FF 64
#define INF __builtin_inff()

typedef __hip_bfloat16 bf16;

// pack two f32 -> bf16x2 dword (RNE), a in low half
__device__ __forceinline__ unsigned pk_bf16x2(float a, float b) {
  union { __hip_bfloat162 h; unsigned u; } cv;
  cv.h.x = __float2bfloat16(a);
  cv.h.y = __float2bfloat16(b);
  return cv.u;
}

// ---------------- row norms: x2[r] = sum_k x[r][k]^2 ----------------
__global__ void norms_k(const float* __restrict__ a, float* __restrict__ o, int rows) {
  int r = blockIdx.x * 256 + threadIdx.x;
  if (r >= rows) return;
  const float4* p = (const float4*)(a + (size_t)r * FF);
  float s = 0.f;
#pragma unroll
  for (int q = 0; q < FF / 4; ++q) {
    float4 v = p[q];
    s = fmaf(v.x, v.x, fmaf(v.y, v.y, fmaf(v.z, v.z, fmaf(v.w, v.w, s))));
  }
  o[r] = s;
}

// ---------------- INF pad column (2048 bf16 = 1024 dwords) ----------------
__global__ void fillinf_k(unsigned* __restrict__ p) {
  p[blockIdx.x * 256 + threadIdx.x] = 0x7F807F80u;  // bf16 +INF pair
}

// ---------------- dist tile kernel ----------------
// 64x64 (i,j) tile per WG; fp32 dot via LDS; writes dist COLUMN-MAJOR bf16:
// dist[b][col][row], col stride NN.
__global__ __launch_bounds__(256) void dist_k(const float* __restrict__ X,
                                              const float* __restrict__ Y,
                                              const float* __restrict__ x2,
                                              const float* __restrict__ y2,
                                              bf16* __restrict__ dist) {
  __shared__ float xs[64][68];   // x tile row-major; reused as staged dist tile
  __shared__ float ysT[64][68];  // y tile transposed: ysT[k][j]
  const int b = blockIdx.z, i0 = blockIdx.y * 64, j0 = blockIdx.x * 64;
  const int tid = threadIdx.x, tx = tid & 15, ty = tid >> 4;
  const float* Xb = X + ((size_t)b * NN + i0) * FF;
  const float* Yb = Y + ((size_t)b * MM + j0) * FF;
#pragma unroll
  for (int rep = 0; rep < 4; ++rep) {
    int row = rep * 16 + ty;
    float4 vx = *(const float4*)(Xb + row * FF + tx * 4);
    *(float4*)&xs[row][tx * 4] = vx;
    float4 vy = *(const float4*)(Yb + row * FF + tx * 4);
    ysT[tx * 4 + 0][row] = vy.x;
    ysT[tx * 4 + 1][row] = vy.y;
    ysT[tx * 4 + 2][row] = vy.z;
    ysT[tx * 4 + 3][row] = vy.w;
  }
  __syncthreads();

  const int il0 = ty * 4, jl0 = tx * 4;
  float c[4][4] = {};
#pragma unroll
  for (int k = 0; k < FF; ++k) {
    float a0 = xs[il0 + 0][k], a1 = xs[il0 + 1][k], a2 = xs[il0 + 2][k], a3 = xs[il0 + 3][k];
    float4 bv = *(const float4*)&ysT[k][jl0];
    c[0][0] = fmaf(a0, bv.x, c[0][0]); c[0][1] = fmaf(a0, bv.y, c[0][1]);
    c[0][2] = fmaf(a0, bv.z, c[0][2]); c[0][3] = fmaf(a0, bv.w, c[0][3]);
    c[1][0] = fmaf(a1, bv.x, c[1][0]); c[1][1] = fmaf(a1, bv.y, c[1][1]);
    c[1][2] = fmaf(a1, bv.z, c[1][2]); c[1][3] = fmaf(a1, bv.w, c[1][3]);
    c[2][0] = fmaf(a2, bv.x, c[2][0]); c[2][1] = fmaf(a2, bv.y, c[2][1]);
    c[2][2] = fmaf(a2, bv.z, c[2][2]); c[2][3] = fmaf(a2, bv.w, c[2][3]);
    c[3][0] = fmaf(a3, bv.x, c[3][0]); c[3][1] = fmaf(a3, bv.y, c[3][1]);
    c[3][2] = fmaf(a3, bv.z, c[3][2]); c[3][3] = fmaf(a3, bv.w, c[3][3]);
  }

  float x2v[4], y2v[4];
#pragma unroll
  for (int p = 0; p < 4; ++p) x2v[p] = x2[b * NN + i0 + il0 + p];
#pragma unroll
  for (int q = 0; q < 4; ++q) y2v[q] = y2[b * MM + j0 + jl0 + q];
  __syncthreads();  // all xs/ysT dot-reads done; safe to overwrite xs
#pragma unroll
  for (int p = 0; p < 4; ++p) {
    float4 r;
    r.x = sqrtf(fmaxf(x2v[p] + y2v[0] - 2.f * c[p][0], 0.f));
    r.y = sqrtf(fmaxf(x2v[p] + y2v[1] - 2.f * c[p][1], 0.f));
    r.z = sqrtf(fmaxf(x2v[p] + y2v[2] - 2.f * c[p][2], 0.f));
    r.w = sqrtf(fmaxf(x2v[p] + y2v[3] - 2.f * c[p][3], 0.f));
    *(float4*)&xs[il0 + p][jl0] = r;
  }
  __syncthreads();

  // transposed write-out: thread -> (column c, row-quarter part); per column the
  // 4 parts give 128B contiguous; per warp 16 columns -> 16 x 128B transactions.
  const int cl = tid >> 2, part = tid & 3;
  unsigned w8[8];
#pragma unroll
  for (int m = 0; m < 8; ++m) {
    int r0 = part * 16 + m * 2;
    w8[m] = pk_bf16x2(xs[r0][cl], xs[r0 + 1][cl]);
  }
  bf16* dst = dist + ((size_t)b * MM + (j0 + cl)) * NN + i0 + part * 16;
  *(uint4*)dst = make_uint4(w8[0], w8[1], w8[2], w8[3]);
  *(uint4*)(dst + 8) = make_uint4(w8[4], w8[5], w8[6], w8[7]);
}

// ---------------- DP: wave-systolic column scan ----------------
// One wave per batch. Lane l owns rows [32l, 32l+32); at tick T it processes
// column j = T - l. Cross-lane: one shfl_up of lane (l-1)'s bottom cell.
// OOB columns read a shared INF column via pointer-select -> no per-tick guards.
#define TICK(K, Lr, Cw, T)                                                                  \
  do {                                                                                      \
    float nt = __shfl_up(bottom, 1, 64);                                                    \
    if (lane == 0) nt = INF;                                                                \
    float chain = nt;                                                                       \
    _Pragma("unroll") for (int r = 0; r < 32; ++r) {                                        \
      const int wi = r >> 1;                                                                \
      uint4 qv = pf[K][wi >> 2];                                                            \
      const int cs = wi & 3;                                                                \
      unsigned dw = cs == 0 ? qv.x : cs == 1 ? qv.y : cs == 2 ? qv.z : qv.w;                \
      float dvf = ((r & 1) == 0) ? __uint_as_float(dw << 16)                                \
                                 : __uint_as_float(dw & 0xFFFF0000u);                       \
      float dg = (r == 0) ? topPrev : Lr[r - 1];                                            \
      float mm = fminf(Lr[r], dg);                                                          \
      float cu = dvf + fminf(mm, chain);                                                    \
      Cw[r] = cu;                                                                           \
      chain = cu;                                                                           \
    }                                                                                       \
    topPrev = nt;                                                                           \
    bottom = chain;                                                                         \
    {                                                                                       \
      int cc = (T) + 4 - lane;                                                              \
      const uint4* p = ((unsigned)cc > (unsigned)(MM - 1))                                  \
                           ? infq                                                           \
                           : (const uint4*)(db + (size_t)cc * NN);                          \
      p += lane * 4;                                                                        \
      pf[K][0] = p[0]; pf[K][1] = p[1]; pf[K][2] = p[2]; pf[K][3] = p[3];                   \
    }                                                                                       \
  } while (0)

__global__ __launch_bounds__(64) void dp_k(const bf16* __restrict__ dist,
                                           const bf16* __restrict__ infcol,
                                           float* __restrict__ out) {
  const int b = blockIdx.x, lane = threadIdx.x;
  const bf16* db = dist + (size_t)b * NN * MM;
  const uint4* infq = (const uint4*)infcol;

  float A[32], B[32];
#pragma unroll
  for (int r = 0; r < 32; ++r) { A[r] = INF; B[r] = INF; }
  float bottom = INF;
  float topPrev = (lane == 0) ? 0.f : INF;  // makes cell (0,0) cand==0 fall out
  uint4 pf[4][4];

  // prologue: fill prefetch slots for ticks 0..3 (cols k-l; negatives -> INF col)
#pragma unroll
  for (int k = 0; k < 4; ++k) {
    int cc = k - lane;
    const uint4* p = ((unsigned)cc > (unsigned)(MM - 1))
                         ? infq
                         : (const uint4*)(db + (size_t)cc * NN);
    p += lane * 4;
    pf[k][0] = p[0]; pf[k][1] = p[1]; pf[k][2] = p[2]; pf[k][3] = p[3];
  }

  // main: ticks 0..2107 (527 blocks of 4), then peel 2108..2110
  for (int tb = 0; tb < 527; ++tb) {
    const int T0 = tb * 4;
    TICK(0, A, B, T0 + 0);
    TICK(1, B, A, T0 + 1);
    TICK(2, A, B, T0 + 2);
    TICK(3, B, A, T0 + 3);
  }
  TICK(0, A, B, 2108);
  TICK(1, B, A, 2109);
  TICK(2, A, B, 2110);  // lane 63 computes column 2047 here -> D[2047][2047] in B[31]

  if (lane == 63) out[b] = B[31];
}

extern "C" void kernel_launch(void* const* d_in, const int* in_sizes, int n_in,
                              void* d_out, int out_size, void* d_ws, size_t ws_size,
                              hipStream_t stream) {
  const float* X = (const float*)d_in[0];
  const float* Y = (const float*)d_in[1];
  float* out = (float*)d_out;

  float* x2 = (float*)d_ws;                              // BB*NN floats
  float* y2 = x2 + BB * NN;                              // BB*MM floats
  bf16* infcol = (bf16*)((char*)d_ws + 131072);          // 2048 bf16 of +INF
  bf16* dist = infcol + 2048;                            // BB*NN*MM bf16, col-major

  norms_k<<<dim3((BB * NN + 255) / 256), dim3(256), 0, stream>>>(X, x2, BB * NN);
  norms_k<<<dim3((BB * MM + 255) / 256), dim3(256), 0, stream>>>(Y, y2, BB * MM);
  fillinf_k<<<dim3(4), dim3(256), 0, stream>>>((unsigned*)infcol);

  dist_k<<<dim3(MM / 64, NN / 64, BB), dim3(256), 0, stream>>>(X, Y, x2, y2, dist);
  dp_k<<<dim3(BB), dim3(64), 0, stream>>>(dist, infcol, out);
}